// Round 4
// baseline (412.500 us; speedup 1.0000x reference)
//
#include <hip/hip_runtime.h>
#include <hip/hip_bf16.h>
#include <math.h>

#define BATCH   4
#define N_KP    1024
#define C_DIM   128
#define HW_     256
#define M_CELLS 1024
#define BIGV    10.0f
#define EPSV    1e-8f

__device__ inline float wsum(float v) {
#pragma unroll
    for (int off = 32; off > 0; off >>= 1) v += __shfl_xor(v, off, 64);
    return v;
}

// branchless insert of x into ascending sorted-8 (keep 8 smallest)
__device__ inline void ins8(float s[8], float x) {
    s[7] = fminf(s[7], x);
#pragma unroll
    for (int t = 7; t >= 1; --t) {
        float lo = fminf(s[t - 1], s[t]);
        float hi = fmaxf(s[t - 1], s[t]);
        s[t - 1] = lo; s[t] = hi;
    }
}

#define CE(a, b) { float _lo = fminf(a, b), _hi = fmaxf(a, b); a = _lo; b = _hi; }

// cross-lane merge: each lane holds ascending sorted-8; after 6 stages all 64
// lanes hold the identical global top-8 (ascending)
__device__ inline void merge64(float s[8]) {
#pragma unroll
    for (int d = 1; d < 64; d <<= 1) {
        float p[8];
#pragma unroll
        for (int i = 0; i < 8; ++i) p[i] = __shfl_xor(s[i], d, 64);
        float m[8];
#pragma unroll
        for (int i = 0; i < 8; ++i) m[i] = fminf(s[i], p[7 - i]);
        CE(m[0], m[4]); CE(m[1], m[5]); CE(m[2], m[6]); CE(m[3], m[7]);
        CE(m[0], m[2]); CE(m[1], m[3]); CE(m[4], m[6]); CE(m[5], m[7]);
        CE(m[0], m[1]); CE(m[2], m[3]); CE(m[4], m[5]); CE(m[6], m[7]);
#pragma unroll
        for (int i = 0; i < 8; ++i) s[i] = m[i];
    }
}

__device__ inline float packkey(float v, int j) {
    return __uint_as_float((__float_as_uint(v) & 0xFFFFFC00u) | (unsigned)j);
}

// ---------------- K1: a = l2n(kp1_desc) + visibility ----------------
__global__ __launch_bounds__(64) void k_prep(const float* __restrict__ desc,
                                             const float* __restrict__ kp1,
                                             const float* __restrict__ homo,
                                             float* __restrict__ a,
                                             float* __restrict__ vis,
                                             float* __restrict__ acc) {
    int row = blockIdx.x;
    int l = threadIdx.x;
    const float2* src = (const float2*)(desc + (size_t)row * C_DIM);
    float2 v = src[l];
    float ss = wsum(v.x * v.x + v.y * v.y);
    float nrm = sqrtf(ss) + EPSV;
    float2* dst = (float2*)(a + (size_t)row * C_DIM);
    dst[l] = make_float2(v.x / nrm, v.y / nrm);
    if (l == 0) {
        int b = row >> 10;
        float x = kp1[(size_t)row * 2];
        float y = kp1[(size_t)row * 2 + 1];
        const float* h = homo + b * 9;
        float u = h[0] * x + h[1] * y + h[2];
        float vv = h[3] * x + h[4] * y + h[5];
        float w = h[6] * x + h[7] * y + h[8];
        float wx_ = u / (w + EPSV);
        float wy_ = vv / (w + EPSV);
        float viz = (wx_ >= 0.f && wx_ <= (float)(HW_ - 1) &&
                     wy_ >= 0.f && wy_ <= (float)(HW_ - 1)) ? 1.f : 0.f;
        vis[row] = viz;
        atomicAdd(&acc[2], viz);
    }
}

// Bilinear gather of 2 channels (c=2l, 2l+1) at (px,py) from desc2[b]
__device__ inline void bilin2(const float* __restrict__ desc2, int b,
                              float px, float py, int l, float* v) {
    float x = fminf(fmaxf(px, 0.f), (float)(HW_ - 1));
    float y = fminf(fmaxf(py, 0.f), (float)(HW_ - 1));
    float x0f = floorf(x), y0f = floorf(y);
    float wx = x - x0f, wy = y - y0f;
    int x0 = (int)x0f, y0 = (int)y0f;
    int x1 = min(x0 + 1, HW_ - 1), y1 = min(y0 + 1, HW_ - 1);
    float w00 = (1.f - wy) * (1.f - wx);
    float w01 = (1.f - wy) * wx;
    float w10 = wy * (1.f - wx);
    float w11 = wy * wx;
#pragma unroll
    for (int t = 0; t < 2; ++t) {
        int c = 2 * l + t;
        const float* p = desc2 + (size_t)(b * C_DIM + c) * HW_ * HW_;
        float v00 = p[y0 * HW_ + x0];
        float v01 = p[y0 * HW_ + x1];
        float v10 = p[y1 * HW_ + x0];
        float v11 = p[y1 * HW_ + x1];
        v[t] = v00 * w00 + v01 * w01 + v10 * w10 + v11 * w11;
    }
}

// ---------------- K2: fused wa (id<4096) + gd (id>=4096) ----------------
__global__ __launch_bounds__(64) void k_gather(const float* __restrict__ wkp,
                                               const float* __restrict__ desc2,
                                               const float* __restrict__ a,
                                               float* __restrict__ waT,   // (B,C,N)
                                               float* __restrict__ waR,   // (B,N,C)
                                               float* __restrict__ gdT,   // (B,C,M)
                                               float* __restrict__ pos) {
    int id = blockIdx.x;
    int l = threadIdx.x;
    if (id < BATCH * N_KP) {
        int row = id;
        int b = row >> 10, n = row & 1023;
        float px = wkp[(size_t)row * 2];
        float py = wkp[(size_t)row * 2 + 1];
        float vals[2];
        bilin2(desc2, b, px, py, l, vals);
        float ss = wsum(vals[0] * vals[0] + vals[1] * vals[1]);
        float nrm = sqrtf(ss) + EPSV;
        float w0 = vals[0] / nrm, w1 = vals[1] / nrm;
        waT[(size_t)(b * C_DIM + 2 * l) * N_KP + n]     = w0;
        waT[(size_t)(b * C_DIM + 2 * l + 1) * N_KP + n] = w1;
        ((float2*)(waR + (size_t)row * C_DIM))[l] = make_float2(w0, w1);
        const float2* ar = (const float2*)(a + (size_t)row * C_DIM);
        float2 av = ar[l];
        float d0 = av.x - w0, d1 = av.y - w1;
        float pp = wsum(d0 * d0 + d1 * d1);
        if (l == 0) pos[row] = sqrtf(pp);
    } else {
        int idx = id - BATCH * N_KP;
        int b = idx >> 10, m = idx & 1023;
        float px = ((float)(m & 31) + 0.5f) * 8.0f;
        float py = ((float)(m >> 5) + 0.5f) * 8.0f;
        float vals[2];
        bilin2(desc2, b, px, py, l, vals);
        float ss = wsum(vals[0] * vals[0] + vals[1] * vals[1]);
        float nrm = sqrtf(ss) + EPSV;
        gdT[(size_t)(b * C_DIM + 2 * l) * M_CELLS + m]     = vals[0] / nrm;
        gdT[(size_t)(b * C_DIM + 2 * l + 1) * M_CELLS + m] = vals[1] / nrm;
    }
}

// ---------------- K3: fused distance-matrix + top-8 + loss ----------------
// blockIdx.z==0: neg/FOS (A=a, G=gdT);  z==1: d2m/SOS (A=waR, G=waT)
// 16 rows x 1024 cols per block; dists live in a 64 KB LDS tile.
__global__ __launch_bounds__(256) void k_mat(const float* __restrict__ a,
                                             const float* __restrict__ gdT,
                                             const float* __restrict__ waT,
                                             const float* __restrict__ waR,
                                             const float* __restrict__ wkp,
                                             const float* __restrict__ pos,
                                             const float* __restrict__ vis,
                                             float* __restrict__ acc) {
    __shared__ float dist[16 * 1024];    // exactly 64 KB
    int b = blockIdx.y;
    int n0 = blockIdx.x * 16;
    int t = threadIdx.x;
    int zsel = blockIdx.z;
    const float* A;
    const float4* G;
    if (zsel == 0) {
        A = a + (size_t)(b * N_KP + n0) * C_DIM;
        G = (const float4*)(gdT + (size_t)b * C_DIM * M_CELLS);
    } else {
        A = waR + (size_t)(b * N_KP + n0) * C_DIM;
        G = (const float4*)(waT + (size_t)b * C_DIM * N_KP);
    }
    float4 s[16];
#pragma unroll
    for (int r = 0; r < 16; ++r) s[r] = make_float4(0.f, 0.f, 0.f, 0.f);
#pragma unroll 2
    for (int c = 0; c < C_DIM; c += 4) {
        float4 g0 = G[(size_t)(c + 0) * 256 + t];
        float4 g1 = G[(size_t)(c + 1) * 256 + t];
        float4 g2 = G[(size_t)(c + 2) * 256 + t];
        float4 g3 = G[(size_t)(c + 3) * 256 + t];
#pragma unroll
        for (int r = 0; r < 16; ++r) {
            float a0 = A[r * C_DIM + c + 0];
            float a1 = A[r * C_DIM + c + 1];
            float a2 = A[r * C_DIM + c + 2];
            float a3 = A[r * C_DIM + c + 3];
            s[r].x += a0 * g0.x + a1 * g1.x + a2 * g2.x + a3 * g3.x;
            s[r].y += a0 * g0.y + a1 * g1.y + a2 * g2.y + a3 * g3.y;
            s[r].z += a0 * g0.z + a1 * g1.z + a2 * g2.z + a3 * g3.z;
            s[r].w += a0 * g0.w + a1 * g1.w + a2 * g2.w + a3 * g3.w;
        }
    }
    // mask + store to LDS
    int j0 = 4 * t;
    if (zsel == 0) {
        float cgx0 = (float)(j0 & 31) * 8.0f + 4.0f,       cgy0 = (float)(j0 >> 5) * 8.0f + 4.0f;
        float cgx1 = (float)((j0 + 1) & 31) * 8.0f + 4.0f, cgy1 = (float)((j0 + 1) >> 5) * 8.0f + 4.0f;
        float cgx2 = (float)((j0 + 2) & 31) * 8.0f + 4.0f, cgy2 = (float)((j0 + 2) >> 5) * 8.0f + 4.0f;
        float cgx3 = (float)((j0 + 3) & 31) * 8.0f + 4.0f, cgy3 = (float)((j0 + 3) >> 5) * 8.0f + 4.0f;
#pragma unroll
        for (int r = 0; r < 16; ++r) {
            float wx = wkp[(size_t)(b * N_KP + n0 + r) * 2];
            float wy = wkp[(size_t)(b * N_KP + n0 + r) * 2 + 1];
            float4 d;
            d.x = sqrtf(fmaxf(2.f - 2.f * s[r].x, 0.f) + EPSV);
            d.y = sqrtf(fmaxf(2.f - 2.f * s[r].y, 0.f) + EPSV);
            d.z = sqrtf(fmaxf(2.f - 2.f * s[r].z, 0.f) + EPSV);
            d.w = sqrtf(fmaxf(2.f - 2.f * s[r].w, 0.f) + EPSV);
            float dx, dy;
            dx = wx - cgx0; dy = wy - cgy0; if (dx * dx + dy * dy < 256.f) d.x = BIGV;
            dx = wx - cgx1; dy = wy - cgy1; if (dx * dx + dy * dy < 256.f) d.y = BIGV;
            dx = wx - cgx2; dy = wy - cgy2; if (dx * dx + dy * dy < 256.f) d.z = BIGV;
            dx = wx - cgx3; dy = wy - cgy3; if (dx * dx + dy * dy < 256.f) d.w = BIGV;
            ((float4*)(dist + r * 1024))[t] = d;
        }
    } else {
        float4 wjA = ((const float4*)(wkp + (size_t)b * N_KP * 2))[2 * t];     // kp j0, j0+1
        float4 wjB = ((const float4*)(wkp + (size_t)b * N_KP * 2))[2 * t + 1]; // kp j0+2, j0+3
#pragma unroll
        for (int r = 0; r < 16; ++r) {
            int n = n0 + r;
            float wx = wkp[(size_t)(b * N_KP + n) * 2];
            float wy = wkp[(size_t)(b * N_KP + n) * 2 + 1];
            float4 d;
            d.x = sqrtf(fmaxf(2.f - 2.f * s[r].x, 0.f) + EPSV);
            d.y = sqrtf(fmaxf(2.f - 2.f * s[r].y, 0.f) + EPSV);
            d.z = sqrtf(fmaxf(2.f - 2.f * s[r].z, 0.f) + EPSV);
            d.w = sqrtf(fmaxf(2.f - 2.f * s[r].w, 0.f) + EPSV);
            float dx, dy;
            dx = wx - wjA.x; dy = wy - wjA.y; if (dx * dx + dy * dy < 256.f || n == j0)     d.x = BIGV;
            dx = wx - wjA.z; dy = wy - wjA.w; if (dx * dx + dy * dy < 256.f || n == j0 + 1) d.y = BIGV;
            dx = wx - wjB.x; dy = wy - wjB.y; if (dx * dx + dy * dy < 256.f || n == j0 + 2) d.z = BIGV;
            dx = wx - wjB.z; dy = wy - wjB.w; if (dx * dx + dy * dy < 256.f || n == j0 + 3) d.w = BIGV;
            ((float4*)(dist + r * 1024))[t] = d;
        }
    }
    __syncthreads();
    // selection: wave w handles rows 4w..4w+3
    int w = t >> 6, l = t & 63;
#pragma unroll 1
    for (int rr = 0; rr < 4; ++rr) {
        int r = 4 * w + rr;
        int row = b * N_KP + n0 + r;
        float s8[8];
#pragma unroll
        for (int k = 0; k < 8; ++k) s8[k] = 1e30f;
        if (zsel == 0) {
#pragma unroll
            for (int k = 0; k < 16; ++k) ins8(s8, dist[r * 1024 + l + 64 * k]);
            merge64(s8);
            if (l == 0) {
                float p = pos[row];
                float sum = 0.f;
#pragma unroll
                for (int q = 0; q < 8; ++q) sum += fmaxf(p - s8[q] + 1.0f, 0.f);
                atomicAdd(&acc[0], sum * vis[row]);
            }
        } else {
#pragma unroll
            for (int k = 0; k < 16; ++k) {
                int j = l + 64 * k;
                ins8(s8, packkey(dist[r * 1024 + j], j));
            }
            merge64(s8);
            float2 av = ((const float2*)(a + (size_t)row * C_DIM))[l];
            float dot[8];
#pragma unroll
            for (int q = 0; q < 8; ++q) {
                int j = (int)(__float_as_uint(s8[q]) & 1023u);
                float2 jv = ((const float2*)(a + (size_t)(b * N_KP + j) * C_DIM))[l];
                dot[q] = av.x * jv.x + av.y * jv.y;
            }
#pragma unroll
            for (int q = 0; q < 8; ++q) dot[q] = wsum(dot[q]);
            float ss2 = 0.f;
#pragma unroll
            for (int q = 0; q < 8; ++q) {
                float d2s = __uint_as_float(__float_as_uint(s8[q]) & 0xFFFFFC00u);
                float d1 = sqrtf(fmaxf(2.f - 2.f * dot[q], 0.f) + EPSV);
                float okv = (d2s < 5.0f) ? 1.f : 0.f;
                float diff = (d1 - d2s) * okv;
                ss2 += diff * diff;
            }
            if (l == 0) atomicAdd(&acc[1], sqrtf(ss2 + EPSV) * vis[row]);
        }
    }
}

// ---------------- K4: finalize ----------------
__global__ void k_fin(const float* __restrict__ acc, float* __restrict__ out) {
    float cnt = fmaxf(acc[2], 1.0f);
    float fos = acc[0] / (cnt * 8.0f);
    float sos = acc[1] / cnt;
    out[0] = fos + sos;
}

extern "C" void kernel_launch(void* const* d_in, const int* in_sizes, int n_in,
                              void* d_out, int out_size, void* d_ws, size_t ws_size,
                              hipStream_t stream) {
    (void)in_sizes; (void)n_in; (void)out_size; (void)ws_size;
    const float* kp1   = (const float*)d_in[0];
    const float* wkp   = (const float*)d_in[1];
    const float* kdesc = (const float*)d_in[2];
    const float* desc2 = (const float*)d_in[3];
    const float* homo  = (const float*)d_in[4];

    float* ws  = (float*)d_ws;
    float* acc = ws;                                   // [0]=fos [1]=sos [2]=cnt
    float* a   = ws + 16;                              // (B,N,C)
    float* waT = a + (size_t)BATCH * N_KP * C_DIM;     // (B,C,N)
    float* waR = waT + (size_t)BATCH * C_DIM * N_KP;   // (B,N,C)
    float* gdT = waR + (size_t)BATCH * N_KP * C_DIM;   // (B,C,M)
    float* pos = gdT + (size_t)BATCH * C_DIM * M_CELLS;
    float* vis = pos + BATCH * N_KP;

    hipMemsetAsync(acc, 0, 16 * sizeof(float), stream);
    k_prep<<<BATCH * N_KP, 64, 0, stream>>>(kdesc, kp1, homo, a, vis, acc);
    k_gather<<<2 * BATCH * N_KP, 64, 0, stream>>>(wkp, desc2, a, waT, waR, gdT, pos);
    k_mat<<<dim3(N_KP / 16, BATCH, 2), 256, 0, stream>>>(a, gdT, waT, waR, wkp, pos, vis, acc);
    k_fin<<<1, 1, 0, stream>>>(acc, (float*)d_out);
}